// Round 9
// baseline (894.862 us; speedup 1.0000x reference)
//
#include <hip/hip_runtime.h>

// SubLSTM R12: MLP row-amortization. Scan untouched (R9-proven, 520us).
//  - mlp_bf16w2_kernel: 128 rows/block (2 A-tiles in REGISTERS, loaded direct
//    from global with in-reg f2bf — same lane mapping as the old LDS path).
//    Weights staged once per nc serve 2 tiles -> weight LDS-reads and L2
//    weight traffic per row HALVED. LDS 63KB -> 2 blocks/CU (cross-block
//    overlap hides staging latency; R11 showed reg-prefetch is not needed).
//  - wprep one-time f32->bf16 weight conversion kept. Fallback (no ws) = R9 MLP.

#define Gn 8
#define Dn 20
#define Bn 64
#define Tn 2000
#define Fn 160
#define NR (Bn * Tn)
#define L2E 1.4426950408889634f
#define WS_W1 0
#define WS_W2 102400
#define WS_NEED (204800 * sizeof(unsigned short))

typedef __attribute__((ext_vector_type(2))) float f32x2;
typedef __attribute__((ext_vector_type(4))) float f32x4;
typedef __attribute__((ext_vector_type(8))) short bf16x8;
typedef __attribute__((ext_vector_type(2))) unsigned u32x2;

__device__ __forceinline__ float rdlane(float v, int k) {
  return __int_as_float(__builtin_amdgcn_readlane(__float_as_int(v), k));
}
__device__ __forceinline__ float xswap(float v) {  // v[lane^32] on lanes 0..31
#if __has_builtin(__builtin_amdgcn_permlane32_swap)
  const u32x2 r = __builtin_amdgcn_permlane32_swap(__float_as_uint(v),
                                                   __float_as_uint(v), false,
                                                   false);
  return __uint_as_float(r.y);  // new vsrc: [lane<32] = old vdst[lane+32]
#else
  return __shfl_xor(v, 32);
#endif
}
__device__ __forceinline__ unsigned short f2bf(float f) {
  unsigned u = __float_as_uint(f);
  u += 0x8000u;
  return (unsigned short)(u >> 16);
}

// Recurrent step (R9-proven form). gzA/gzB: prescaled input-proj+bias.
// A rows (i,f) and B o rows prescaled by -log2e; B g rows by +2*log2e.
__device__ __forceinline__ void rec2(float gzA, float gzB,
                                     const f32x2* __restrict__ WPA,
                                     const f32x2* __restrict__ WPB, float& h,
                                     float& c) {
  f32x2 hp[10];
#pragma unroll
  for (int j = 0; j < 10; ++j) {
    hp[j].x = rdlane(h, 2 * j);      // wave-uniform -> SGPR
    hp[j].y = rdlane(h, 2 * j + 1);  // pair -> VOP3P scalar operand
  }
  f32x2 aA;
  aA.x = gzA;
  aA.y = 0.f;
  f32x2 aB;
  aB.x = gzB;
  aB.y = 0.f;
#pragma unroll
  for (int j = 0; j < 10; ++j) {
    aA = __builtin_elementwise_fma(WPA[j], hp[j], aA);
    aB = __builtin_elementwise_fma(WPB[j], hp[j], aB);
  }
  const float zA = aA.x + aA.y;
  const float zB = aB.x + aB.y;
  const float rA = __builtin_amdgcn_rcpf(1.f + __builtin_amdgcn_exp2f(zA));
  const float rB = __builtin_amdgcn_rcpf(1.f + __builtin_amdgcn_exp2f(zB));
  const float sF = xswap(rA);  // f-sigmoid for lanes 0..19
  const float sO = xswap(rB);  // o-sigmoid for lanes 0..19
  const float tG = __builtin_fmaf(-2.f, rB, 1.f);  // tanh(g), own lane
  c = sF * c + rA * tG;                            // sI = rA (own lane)
  const float tC = __builtin_fmaf(
      -2.f, __builtin_amdgcn_rcpf(1.f + __builtin_amdgcn_exp2f((2.f * L2E) * c)),
      1.f);
  h = sO * tC;
}

// Projection step (R9-proven form): z = W*row + bias (prescaled).
__device__ __forceinline__ void proj2(const float* __restrict__ row,
                                      const f32x2* __restrict__ WPA,
                                      const f32x2* __restrict__ WPB, float bzA,
                                      float bzB, float* dA, float* dB) {
  const f32x4 x0 = *(const f32x4*)&row[0];
  const f32x4 x1 = *(const f32x4*)&row[4];
  const f32x4 x2 = *(const f32x4*)&row[8];
  const f32x4 x3 = *(const f32x4*)&row[12];
  const f32x4 x4 = *(const f32x4*)&row[16];
  f32x2 xp[10];
  xp[0] = __builtin_shufflevector(x0, x0, 0, 1);
  xp[1] = __builtin_shufflevector(x0, x0, 2, 3);
  xp[2] = __builtin_shufflevector(x1, x1, 0, 1);
  xp[3] = __builtin_shufflevector(x1, x1, 2, 3);
  xp[4] = __builtin_shufflevector(x2, x2, 0, 1);
  xp[5] = __builtin_shufflevector(x2, x2, 2, 3);
  xp[6] = __builtin_shufflevector(x3, x3, 0, 1);
  xp[7] = __builtin_shufflevector(x3, x3, 2, 3);
  xp[8] = __builtin_shufflevector(x4, x4, 0, 1);
  xp[9] = __builtin_shufflevector(x4, x4, 2, 3);
  f32x2 aA;
  aA.x = bzA;
  aA.y = 0.f;
  f32x2 aB;
  aB.x = bzB;
  aB.y = 0.f;
#pragma unroll
  for (int j = 0; j < 10; ++j) {
    aA = __builtin_elementwise_fma(WPA[j], xp[j], aA);
    aB = __builtin_elementwise_fma(WPB[j], xp[j], aB);
  }
  *dA = aA.x + aA.y;
  *dB = aB.x + aB.y;
}

// One block (512 thr = 8 waves) per 2 chains; 256 blocks -> 2048 waves.
__global__ __launch_bounds__(512) void scan4p_kernel(
    const float* __restrict__ x, const float* __restrict__ Wih0,
    const float* __restrict__ Whh0, const float* __restrict__ bih0,
    const float* __restrict__ bhh0, const float* __restrict__ Wih1,
    const float* __restrict__ Whh1, const float* __restrict__ bih1,
    const float* __restrict__ bhh1, float* __restrict__ out) {
  __shared__ __align__(16) float XS[2][64][20];    // x ring: 8 chunks of 8 steps
  __shared__ __align__(16) float XW0[2][16][128];  // layer0 input-proj ring
  __shared__ __align__(16) float XW1[2][16][128];  // layer1 input-proj ring
  __shared__ __align__(16) float H0[2][16][20];    // h0 ring

  const int tid = threadIdx.x;
  const int lane = tid & 63;
  const int wv = tid >> 6;  // 0..7
  const int sub = wv >> 2;  // chain-in-block
  const int wr = wv & 3;
  const int role = sub ? (3 - wr) : wr;  // SIMD i: {chain0 role i, chain1 role 3-i}
  const int chain = blockIdx.x * 2 + sub;
  const int g = chain >> 6;
  const int b = chain & 63;

  float (*const xs)[20] = XS[sub];
  float (*const xw0)[128] = XW0[sub];
  float (*const xw1)[128] = XW1[sub];
  float (*const h0r)[20] = H0[sub];

  const bool wl = lane < Dn;

  // Gate-row remap: A rows {i: lanes 0..19 -> row d; f: lanes 32..51 -> row 20+d}
  //                 B rows {g: lanes 0..19 -> row 40+d; o: lanes 32..51 -> row 60+d}
  int rowA, rowB;
  float sAc, sBc;
  if (lane < 20) {
    rowA = lane; rowB = lane + 40; sAc = -L2E; sBc = 2.f * L2E;
  } else if (lane >= 32 && lane < 52) {
    rowA = lane - 12; rowB = lane + 28; sAc = -L2E; sBc = -L2E;
  } else {
    rowA = 0; rowB = 0; sAc = 0.f; sBc = 0.f;
  }

  f32x2 WPA[10], WPB[10];
  float bzA = 0.f, bzB = 0.f;
  {
    const float* Wsrc;
    const float* bi = nullptr;
    const float* bh = nullptr;
    if (role == 0) {
      Wsrc = Wih0; bi = bih0; bh = bhh0;
    } else if (role == 1) {
      Wsrc = Whh0;
    } else if (role == 2) {
      Wsrc = Wih1; bi = bih1; bh = bhh1;
    } else {
      Wsrc = Whh1;
    }
    const float* Wg = Wsrc + g * 1600;
#pragma unroll
    for (int j = 0; j < 10; ++j) {
      WPA[j].x = Wg[rowA * 20 + 2 * j] * sAc;
      WPA[j].y = Wg[rowA * 20 + 2 * j + 1] * sAc;
      WPB[j].x = Wg[rowB * 20 + 2 * j] * sBc;
      WPB[j].y = Wg[rowB * 20 + 2 * j + 1] * sBc;
    }
    if (bi) {
      bzA = (bi[g * 80 + rowA] + bh[g * 80 + rowA]) * sAc;
      bzB = (bi[g * 80 + rowB] + bh[g * 80 + rowB]) * sBc;
    }
  }

  if (role & 1) __builtin_amdgcn_s_setprio(1);  // favor the recurrent waves

  const long long cbase = (long long)b * (Tn * Fn) + g * Dn;

  // x-staging lane constants (role0): 160 floats per chunk over 64 lanes.
  int st_t[3], st_d[3];
  bool st_v[3];
#pragma unroll
  for (int i = 0; i < 3; ++i) {
    const int idx = lane + 64 * i;
    st_v[i] = idx < 160;
    st_t[i] = idx / 20;
    st_d[i] = idx % 20;
  }

  if (role == 0) {  // prologue: stage chunk 0
#pragma unroll
    for (int i = 0; i < 3; ++i)
      if (st_v[i])
        xs[st_t[i]][st_d[i]] = x[cbase + (long long)st_t[i] * Fn + st_d[i]];
  }
  __syncthreads();

  float h = 0.f, c = 0.f;

  // role r processes chunk (cix - r); 250 chunks of 8 steps; 1 barrier/iter.
  for (int cix = 0; cix <= 252; ++cix) {
    if (role == 0) {
      const int cs = cix + 1;  // chunk to stage this iteration
      const bool dostage = (cs <= 249);
      float sv[3];
      if (dostage) {  // issue global loads early; LDS writes after compute
#pragma unroll
        for (int i = 0; i < 3; ++i)
          if (st_v[i])
            sv[i] = x[cbase + (long long)(cs * 8 + st_t[i]) * Fn + st_d[i]];
      }
      if (cix <= 249) {
        const float* xsp = &xs[(cix * 8) & 63][0];
        float* xwp = &xw0[(cix * 8) & 15][0];
#pragma unroll
        for (int p = 0; p < 8; ++p)
          proj2(&xsp[p * 20], WPA, WPB, bzA, bzB, &xwp[p * 128 + lane],
                &xwp[p * 128 + 64 + lane]);
      }
      if (dostage) {
        float* xsw = &xs[(cs * 8) & 63][0];
#pragma unroll
        for (int i = 0; i < 3; ++i)
          if (st_v[i]) xsw[st_t[i] * 20 + st_d[i]] = sv[i];
      }
    } else if (role == 1) {
      if (cix >= 1 && cix <= 250) {
        const float* xwp = &xw0[((cix - 1) * 8) & 15][0];
        float* hrw = &h0r[((cix - 1) * 8) & 15][0];
        float gzA[8], gzB[8];
#pragma unroll
        for (int p = 0; p < 8; ++p) {  // hoist ring reads off the serial path
          gzA[p] = xwp[p * 128 + lane];
          gzB[p] = xwp[p * 128 + 64 + lane];
        }
#pragma unroll
        for (int p = 0; p < 8; ++p) {
          rec2(gzA[p], gzB[p], WPA, WPB, h, c);
          if (wl) hrw[p * 20 + lane] = h;
        }
      }
    } else if (role == 2) {
      if (cix >= 2 && cix <= 251) {
        const float* hrp = &h0r[((cix - 2) * 8) & 15][0];
        float* xwp = &xw1[((cix - 2) * 8) & 15][0];
#pragma unroll
        for (int p = 0; p < 8; ++p)
          proj2(&hrp[p * 20], WPA, WPB, bzA, bzB, &xwp[p * 128 + lane],
                &xwp[p * 128 + 64 + lane]);
      }
    } else {
      if (cix >= 3) {
        const int c8 = (cix - 3) * 8;
        const int rl = wl ? lane : 0;
        const float* xwp = &xw1[c8 & 15][0];
        const float* xsp = &xs[c8 & 63][0];
        float gzA[8], gzB[8], xr[8];
#pragma unroll
        for (int p = 0; p < 8; ++p) {
          gzA[p] = xwp[p * 128 + lane];
          gzB[p] = xwp[p * 128 + 64 + lane];
          xr[p] = xsp[p * 20 + rl];  // residual x
        }
#pragma unroll
        for (int p = 0; p < 8; ++p) {
          rec2(gzA[p], gzB[p], WPA, WPB, h, c);
          if (wl) out[cbase + (long long)(c8 + p) * Fn + lane] = h + xr[p];
        }
      }
    }
    __syncthreads();  // single chunk-boundary barrier (outside role divergence)
  }
}

// ---- one-time weight f32->bf16 conversion into workspace ----
__global__ __launch_bounds__(256) void wprep_kernel(
    const float* __restrict__ W1, const float* __restrict__ W2,
    unsigned short* __restrict__ wb) {
  const int t = blockIdx.x * 256 + threadIdx.x;  // 51200 threads x 4 elems
  const float4 v = (t < 25600) ? *(const float4*)(W1 + t * 4)
                               : *(const float4*)(W2 + (t - 25600) * 4);
  *(ushort4*)(wb + t * 4) =
      make_ushort4(f2bf(v.x), f2bf(v.y), f2bf(v.z), f2bf(v.w));
}

// ---- MFMA bf16 MLP: 128 rows/block, A in registers, weights LDS-amortized ----
__global__ __launch_bounds__(256) void mlp_bf16w2_kernel(
    float* io, const unsigned short* __restrict__ wb,
    const float* __restrict__ b1, const float* __restrict__ b2) {
  __shared__ short Wb[64 * 168];
  __shared__ short W2b[160 * 72];
  __shared__ short Hb[2][64 * 72];
  const unsigned short* __restrict__ W1b = wb + WS_W1;
  const unsigned short* __restrict__ W2s = wb + WS_W2;
  const int tid = threadIdx.x;
  const int lane = tid & 63;
  const int wv = tid >> 6;
  const long long r0 = (long long)blockIdx.x * 128;
  const int cl = lane & 15;
  const int q8 = (lane >> 4) * 8;
  const int ar = wv * 16 + cl;
  const int hrow0 = wv * 16 + (lane >> 4) * 4;

  // A fragments direct from global (same lane->element map as the LDS path).
  bf16x8 afr0[5], afr1[5];
#pragma unroll
  for (int kk = 0; kk < 5; ++kk) {
    const long long row0 = (r0 + ar) * (long long)Fn;
    const long long row1 = (r0 + 64 + ar) * (long long)Fn;
    const float4 a0 = *(const float4*)(io + row0 + kk * 32 + q8);
    const float4 a1 = *(const float4*)(io + row0 + kk * 32 + q8 + 4);
    const float4 c0 = *(const float4*)(io + row1 + kk * 32 + q8);
    const float4 c1 = *(const float4*)(io + row1 + kk * 32 + q8 + 4);
    union { ushort4 u4[2]; bf16x8 v; } u;
    u.u4[0] = make_ushort4(f2bf(a0.x), f2bf(a0.y), f2bf(a0.z), f2bf(a0.w));
    u.u4[1] = make_ushort4(f2bf(a1.x), f2bf(a1.y), f2bf(a1.z), f2bf(a1.w));
    afr0[kk] = u.v;
    u.u4[0] = make_ushort4(f2bf(c0.x), f2bf(c0.y), f2bf(c0.z), f2bf(c0.w));
    u.u4[1] = make_ushort4(f2bf(c1.x), f2bf(c1.y), f2bf(c1.z), f2bf(c1.w));
    afr1[kk] = u.v;
  }

  f32x4 acc0[10], acc1[10];
#pragma unroll
  for (int n = 0; n < 10; ++n) {
    acc0[n] = (f32x4){0.f, 0.f, 0.f, 0.f};
    acc1[n] = (f32x4){0.f, 0.f, 0.f, 0.f};
  }

  for (int nc = 0; nc < 10; ++nc) {
    if (nc) __syncthreads();  // prior nc's weight LDS reads complete
#pragma unroll
    for (int i = 0; i < 10; ++i) {  // stage W1 chunk (64x160 bf16)
      const int idx = tid + i * 256;
      *(ushort4*)&Wb[(idx / 40) * 168 + (idx % 40) * 4] =
          *(const ushort4*)(W1b + (nc * 64 + idx / 40) * 160 + (idx % 40) * 4);
    }
#pragma unroll
    for (int i = 0; i < 10; ++i) {  // stage W2 chunk (160x64 bf16)
      const int idx = tid + i * 256;
      *(ushort4*)&W2b[(idx >> 4) * 72 + (idx & 15) * 4] =
          *(const ushort4*)(W2s + (idx >> 4) * 640 + nc * 64 + (idx & 15) * 4);
    }
    __syncthreads();
    // layer 1: weight fragments loaded once, used for BOTH tiles
#pragma unroll
    for (int n16 = 0; n16 < 4; ++n16) {
      const int br = n16 * 16 + cl;
      bf16x8 bfr[5];
#pragma unroll
      for (int kk = 0; kk < 5; ++kk)
        bfr[kk] = *(const bf16x8*)&Wb[br * 168 + kk * 32 + q8];
      f32x4 h0 = (f32x4){0.f, 0.f, 0.f, 0.f};
      f32x4 h1 = (f32x4){0.f, 0.f, 0.f, 0.f};
#pragma unroll
      for (int kk = 0; kk < 5; ++kk) {
        h0 = __builtin_amdgcn_mfma_f32_16x16x32_bf16(afr0[kk], bfr[kk], h0, 0, 0, 0);
        h1 = __builtin_amdgcn_mfma_f32_16x16x32_bf16(afr1[kk], bfr[kk], h1, 0, 0, 0);
      }
      const float b1v = b1[nc * 64 + n16 * 16 + cl];
      const int hcol = n16 * 16 + cl;
#pragma unroll
      for (int r = 0; r < 4; ++r) {
        Hb[0][(hrow0 + r) * 72 + hcol] = f2bf(fmaxf(h0[r] + b1v, 0.f));
        Hb[1][(hrow0 + r) * 72 + hcol] = f2bf(fmaxf(h1[r] + b1v, 0.f));
      }
    }
    // layer 2 (Hb rows are wave-private: intra-wave write->read, no barrier)
    bf16x8 a20[2], a21[2];
#pragma unroll
    for (int kk = 0; kk < 2; ++kk) {
      a20[kk] = *(const bf16x8*)&Hb[0][ar * 72 + kk * 32 + q8];
      a21[kk] = *(const bf16x8*)&Hb[1][ar * 72 + kk * 32 + q8];
    }
#pragma unroll
    for (int n16 = 0; n16 < 10; ++n16) {
      const int br = n16 * 16 + cl;
#pragma unroll
      for (int kk = 0; kk < 2; ++kk) {
        const bf16x8 b2f = *(const bf16x8*)&W2b[br * 72 + kk * 32 + q8];
        acc0[n16] = __builtin_amdgcn_mfma_f32_16x16x32_bf16(a20[kk], b2f, acc0[n16], 0, 0, 0);
        acc1[n16] = __builtin_amdgcn_mfma_f32_16x16x32_bf16(a21[kk], b2f, acc1[n16], 0, 0, 0);
      }
    }
  }
  const int orow0 = wv * 16 + (lane >> 4) * 4;
#pragma unroll
  for (int n16 = 0; n16 < 10; ++n16) {
    const float b2v = b2[n16 * 16 + cl];
#pragma unroll
    for (int r = 0; r < 4; ++r) {
      io[(r0 + orow0 + r) * Fn + n16 * 16 + cl] = acc0[n16][r] + b2v;
      io[(r0 + 64 + orow0 + r) * Fn + n16 * 16 + cl] = acc1[n16][r] + b2v;
    }
  }
}

// ---- fallback MLP (R9-proven): f32 weights, per-block conversion ----
__global__ __launch_bounds__(256) void mlp_mfma_kernel(
    float* io, const float* __restrict__ W1, const float* __restrict__ b1,
    const float* __restrict__ W2, const float* __restrict__ b2) {
  __shared__ short Ab[64 * 168];
  __shared__ short Wb[64 * 168];
  __shared__ short Hb[64 * 72];
  __shared__ short W2b[160 * 72];
  const int tid = threadIdx.x;
  const int lane = tid & 63;
  const int wv = tid >> 6;
  const long long r0 = (long long)blockIdx.x * 64;

#pragma unroll
  for (int i = 0; i < 10; ++i) {
    const int idx = tid + i * 256;
    const int r = idx / 40, kq = idx % 40;
    const float4 v = *(const float4*)(io + (r0 + r) * Fn + kq * 4);
    *(ushort4*)&Ab[r * 168 + kq * 4] =
        make_ushort4(f2bf(v.x), f2bf(v.y), f2bf(v.z), f2bf(v.w));
  }
  __syncthreads();

  const int cl = lane & 15;
  const int q8 = (lane >> 4) * 8;
  const int ar = wv * 16 + cl;
  bf16x8 afr[5];
#pragma unroll
  for (int kk = 0; kk < 5; ++kk)
    afr[kk] = *(const bf16x8*)&Ab[ar * 168 + kk * 32 + q8];

  f32x4 acc[10];
#pragma unroll
  for (int n = 0; n < 10; ++n) acc[n] = (f32x4){0.f, 0.f, 0.f, 0.f};

  for (int nc = 0; nc < 10; ++nc) {
    if (nc) __syncthreads();
#pragma unroll
    for (int i = 0; i < 10; ++i) {
      const int idx = tid + i * 256;
      const int r = idx / 40, kq = idx % 40;
      const float4 v = *(const float4*)(W1 + (nc * 64 + r) * Fn + kq * 4);
      *(ushort4*)&Wb[r * 168 + kq * 4] =
          make_ushort4(f2bf(v.x), f2bf(v.y), f2bf(v.z), f2bf(v.w));
    }
#pragma unroll
    for (int i = 0; i < 10; ++i) {
      const int idx = tid + i * 256;
      const int n = idx >> 4, kq = idx & 15;
      const float4 v = *(const float4*)(W2 + n * 640 + nc * 64 + kq * 4);
      *(ushort4*)&W2b[n * 72 + kq * 4] =
          make_ushort4(f2bf(v.x), f2bf(v.y), f2bf(v.z), f2bf(v.w));
    }
    __syncthreads();
#pragma unroll
    for (int n16 = 0; n16 < 4; ++n16) {
      f32x4 hcc = (f32x4){0.f, 0.f, 0.f, 0.f};
      const int br = n16 * 16 + cl;
#pragma unroll
      for (int kk = 0; kk < 5; ++kk) {
        const bf16x8 bfr = *(const bf16x8*)&Wb[br * 168 + kk * 32 + q8];
        hcc = __builtin_amdgcn_mfma_f32_16x16x32_bf16(afr[kk], bfr, hcc, 0, 0, 0);
      }
      const float b1v = b1[nc * 64 + n16 * 16 + cl];
      const int hrow0 = wv * 16 + (lane >> 4) * 4;
      const int hcol = n16 * 16 + cl;
#pragma unroll
      for (int r = 0; r < 4; ++r)
        Hb[(hrow0 + r) * 72 + hcol] = f2bf(fmaxf(hcc[r] + b1v, 0.f));
    }
    bf16x8 a2[2];
#pragma unroll
    for (int kk = 0; kk < 2; ++kk)
      a2[kk] = *(const bf16x8*)&Hb[ar * 72 + kk * 32 + q8];
#pragma unroll
    for (int n16 = 0; n16 < 10; ++n16) {
      const int br = n16 * 16 + cl;
#pragma unroll
      for (int kk = 0; kk < 2; ++kk) {
        const bf16x8 b2f = *(const bf16x8*)&W2b[br * 72 + kk * 32 + q8];
        acc[n16] = __builtin_amdgcn_mfma_f32_16x16x32_bf16(a2[kk], b2f, acc[n16], 0, 0, 0);
      }
    }
  }
  const int orow0 = wv * 16 + (lane >> 4) * 4;
#pragma unroll
  for (int n16 = 0; n16 < 10; ++n16) {
    const float b2v = b2[n16 * 16 + cl];
#pragma unroll
    for (int r = 0; r < 4; ++r)
      io[(r0 + orow0 + r) * Fn + n16 * 16 + cl] = acc[n16][r] + b2v;
  }
}

extern "C" void kernel_launch(void* const* d_in, const int* in_sizes, int n_in,
                              void* d_out, int out_size, void* d_ws, size_t ws_size,
                              hipStream_t stream) {
  const float* x    = (const float*)d_in[0];
  const float* Wih0 = (const float*)d_in[1];
  const float* Whh0 = (const float*)d_in[2];
  const float* bih0 = (const float*)d_in[3];
  const float* bhh0 = (const float*)d_in[4];
  const float* Wih1 = (const float*)d_in[5];
  const float* Whh1 = (const float*)d_in[6];
  const float* bih1 = (const float*)d_in[7];
  const float* bhh1 = (const float*)d_in[8];
  const float* W1   = (const float*)d_in[9];
  const float* b1   = (const float*)d_in[10];
  const float* W2   = (const float*)d_in[11];
  const float* b2   = (const float*)d_in[12];
  float* out = (float*)d_out;

  const bool fast = (d_ws != nullptr) && (ws_size >= WS_NEED);
  if (fast)  // weight conversion first (no dependence on scan output)
    wprep_kernel<<<dim3(200), dim3(256), 0, stream>>>(
        W1, W2, (unsigned short*)d_ws);

  scan4p_kernel<<<dim3(256), dim3(512), 0, stream>>>(
      x, Wih0, Whh0, bih0, bhh0, Wih1, Whh1, bih1, bhh1, out);

  if (fast)
    mlp_bf16w2_kernel<<<dim3(NR / 128), dim3(256), 0, stream>>>(
        out, (const unsigned short*)d_ws, b1, b2);
  else
    mlp_mfma_kernel<<<dim3(NR / 64), dim3(256), 0, stream>>>(out, W1, b1, W2, b2);
}

// Round 10
// 670.406 us; speedup vs baseline: 1.3348x; 1.3348x over previous
//
#include <hip/hip_runtime.h>

// SubLSTM R13: revert MLP to the proven R10 mlp_bf16w (R12's 2-tile variant
// regressed 165->~355us: VGPR blowup + uncoalesced direct-global A loads).
// Scan: single parameter change Kc 8->16 on the proven R9/R11 structure —
// halves barrier count (253->128), doubles hoist/issue batching. Rings
// re-derived: XS 5 live chunks -> [128][20] (&127); XW0/XW1 -> [32][128]
// (&31); H0 -> [32][20]. LDS 45.5->89KB, still 1 block/CU (256 blocks).

#define Gn 8
#define Dn 20
#define Bn 64
#define Tn 2000
#define Fn 160
#define NR (Bn * Tn)
#define L2E 1.4426950408889634f
#define WS_W1 0
#define WS_W2 102400
#define WS_NEED (204800 * sizeof(unsigned short))

typedef __attribute__((ext_vector_type(2))) float f32x2;
typedef __attribute__((ext_vector_type(4))) float f32x4;
typedef __attribute__((ext_vector_type(8))) short bf16x8;
typedef __attribute__((ext_vector_type(2))) unsigned u32x2;

__device__ __forceinline__ float rdlane(float v, int k) {
  return __int_as_float(__builtin_amdgcn_readlane(__float_as_int(v), k));
}
__device__ __forceinline__ float xswap(float v) {  // v[lane^32] on lanes 0..31
#if __has_builtin(__builtin_amdgcn_permlane32_swap)
  const u32x2 r = __builtin_amdgcn_permlane32_swap(__float_as_uint(v),
                                                   __float_as_uint(v), false,
                                                   false);
  return __uint_as_float(r.y);  // new vsrc: [lane<32] = old vdst[lane+32]
#else
  return __shfl_xor(v, 32);
#endif
}
__device__ __forceinline__ unsigned short f2bf(float f) {
  unsigned u = __float_as_uint(f);
  u += 0x8000u;
  return (unsigned short)(u >> 16);
}

// Recurrent step (R9-proven form). gzA/gzB: prescaled input-proj+bias.
// A rows (i,f) and B o rows prescaled by -log2e; B g rows by +2*log2e.
__device__ __forceinline__ void rec2(float gzA, float gzB,
                                     const f32x2* __restrict__ WPA,
                                     const f32x2* __restrict__ WPB, float& h,
                                     float& c) {
  f32x2 hp[10];
#pragma unroll
  for (int j = 0; j < 10; ++j) {
    hp[j].x = rdlane(h, 2 * j);      // wave-uniform -> SGPR
    hp[j].y = rdlane(h, 2 * j + 1);  // pair -> VOP3P scalar operand
  }
  f32x2 aA;
  aA.x = gzA;
  aA.y = 0.f;
  f32x2 aB;
  aB.x = gzB;
  aB.y = 0.f;
#pragma unroll
  for (int j = 0; j < 10; ++j) {
    aA = __builtin_elementwise_fma(WPA[j], hp[j], aA);
    aB = __builtin_elementwise_fma(WPB[j], hp[j], aB);
  }
  const float zA = aA.x + aA.y;
  const float zB = aB.x + aB.y;
  const float rA = __builtin_amdgcn_rcpf(1.f + __builtin_amdgcn_exp2f(zA));
  const float rB = __builtin_amdgcn_rcpf(1.f + __builtin_amdgcn_exp2f(zB));
  const float sF = xswap(rA);  // f-sigmoid for lanes 0..19
  const float sO = xswap(rB);  // o-sigmoid for lanes 0..19
  const float tG = __builtin_fmaf(-2.f, rB, 1.f);  // tanh(g), own lane
  c = sF * c + rA * tG;                            // sI = rA (own lane)
  const float tC = __builtin_fmaf(
      -2.f, __builtin_amdgcn_rcpf(1.f + __builtin_amdgcn_exp2f((2.f * L2E) * c)),
      1.f);
  h = sO * tC;
}

// Projection step (R9-proven form): z = W*row + bias (prescaled).
__device__ __forceinline__ void proj2(const float* __restrict__ row,
                                      const f32x2* __restrict__ WPA,
                                      const f32x2* __restrict__ WPB, float bzA,
                                      float bzB, float* dA, float* dB) {
  const f32x4 x0 = *(const f32x4*)&row[0];
  const f32x4 x1 = *(const f32x4*)&row[4];
  const f32x4 x2 = *(const f32x4*)&row[8];
  const f32x4 x3 = *(const f32x4*)&row[12];
  const f32x4 x4 = *(const f32x4*)&row[16];
  f32x2 xp[10];
  xp[0] = __builtin_shufflevector(x0, x0, 0, 1);
  xp[1] = __builtin_shufflevector(x0, x0, 2, 3);
  xp[2] = __builtin_shufflevector(x1, x1, 0, 1);
  xp[3] = __builtin_shufflevector(x1, x1, 2, 3);
  xp[4] = __builtin_shufflevector(x2, x2, 0, 1);
  xp[5] = __builtin_shufflevector(x2, x2, 2, 3);
  xp[6] = __builtin_shufflevector(x3, x3, 0, 1);
  xp[7] = __builtin_shufflevector(x3, x3, 2, 3);
  xp[8] = __builtin_shufflevector(x4, x4, 0, 1);
  xp[9] = __builtin_shufflevector(x4, x4, 2, 3);
  f32x2 aA;
  aA.x = bzA;
  aA.y = 0.f;
  f32x2 aB;
  aB.x = bzB;
  aB.y = 0.f;
#pragma unroll
  for (int j = 0; j < 10; ++j) {
    aA = __builtin_elementwise_fma(WPA[j], xp[j], aA);
    aB = __builtin_elementwise_fma(WPB[j], xp[j], aB);
  }
  *dA = aA.x + aA.y;
  *dB = aB.x + aB.y;
}

// One block (512 thr = 8 waves) per 2 chains; 256 blocks -> 2048 waves.
// Kc=16: 125 chunks, 128 loop iters, 1 barrier/iter.
__global__ __launch_bounds__(512) void scan4p_kernel(
    const float* __restrict__ x, const float* __restrict__ Wih0,
    const float* __restrict__ Whh0, const float* __restrict__ bih0,
    const float* __restrict__ bhh0, const float* __restrict__ Wih1,
    const float* __restrict__ Whh1, const float* __restrict__ bih1,
    const float* __restrict__ bhh1, float* __restrict__ out) {
  __shared__ __align__(16) float XS[2][128][20];   // x ring: 8 chunks of 16 steps
  __shared__ __align__(16) float XW0[2][32][128];  // layer0 input-proj ring (2 chunks)
  __shared__ __align__(16) float XW1[2][32][128];  // layer1 input-proj ring (2 chunks)
  __shared__ __align__(16) float H0[2][32][20];    // h0 ring (2 chunks)

  const int tid = threadIdx.x;
  const int lane = tid & 63;
  const int wv = tid >> 6;  // 0..7
  const int sub = wv >> 2;  // chain-in-block
  const int wr = wv & 3;
  const int role = sub ? (3 - wr) : wr;  // SIMD i: {chain0 role i, chain1 role 3-i}
  const int chain = blockIdx.x * 2 + sub;
  const int g = chain >> 6;
  const int b = chain & 63;

  float (*const xs)[20] = XS[sub];
  float (*const xw0)[128] = XW0[sub];
  float (*const xw1)[128] = XW1[sub];
  float (*const h0r)[20] = H0[sub];

  const bool wl = lane < Dn;

  // Gate-row remap: A rows {i: lanes 0..19 -> row d; f: lanes 32..51 -> row 20+d}
  //                 B rows {g: lanes 0..19 -> row 40+d; o: lanes 32..51 -> row 60+d}
  int rowA, rowB;
  float sAc, sBc;
  if (lane < 20) {
    rowA = lane; rowB = lane + 40; sAc = -L2E; sBc = 2.f * L2E;
  } else if (lane >= 32 && lane < 52) {
    rowA = lane - 12; rowB = lane + 28; sAc = -L2E; sBc = -L2E;
  } else {
    rowA = 0; rowB = 0; sAc = 0.f; sBc = 0.f;
  }

  f32x2 WPA[10], WPB[10];
  float bzA = 0.f, bzB = 0.f;
  {
    const float* Wsrc;
    const float* bi = nullptr;
    const float* bh = nullptr;
    if (role == 0) {
      Wsrc = Wih0; bi = bih0; bh = bhh0;
    } else if (role == 1) {
      Wsrc = Whh0;
    } else if (role == 2) {
      Wsrc = Wih1; bi = bih1; bh = bhh1;
    } else {
      Wsrc = Whh1;
    }
    const float* Wg = Wsrc + g * 1600;
#pragma unroll
    for (int j = 0; j < 10; ++j) {
      WPA[j].x = Wg[rowA * 20 + 2 * j] * sAc;
      WPA[j].y = Wg[rowA * 20 + 2 * j + 1] * sAc;
      WPB[j].x = Wg[rowB * 20 + 2 * j] * sBc;
      WPB[j].y = Wg[rowB * 20 + 2 * j + 1] * sBc;
    }
    if (bi) {
      bzA = (bi[g * 80 + rowA] + bh[g * 80 + rowA]) * sAc;
      bzB = (bi[g * 80 + rowB] + bh[g * 80 + rowB]) * sBc;
    }
  }

  if (role & 1) __builtin_amdgcn_s_setprio(1);  // favor the recurrent waves

  const long long cbase = (long long)b * (Tn * Fn) + g * Dn;

  // x-staging lane constants (role0): 320 floats per chunk over 64 lanes (5 each).
  int st_t[5], st_d[5];
#pragma unroll
  for (int i = 0; i < 5; ++i) {
    const int idx = lane + 64 * i;
    st_t[i] = idx / 20;  // 0..15
    st_d[i] = idx % 20;
  }

  if (role == 0) {  // prologue: stage chunk 0
#pragma unroll
    for (int i = 0; i < 5; ++i)
      xs[st_t[i]][st_d[i]] = x[cbase + (long long)st_t[i] * Fn + st_d[i]];
  }
  __syncthreads();

  float h = 0.f, c = 0.f;

  // role r processes chunk (cix - r); 125 chunks of 16 steps; 1 barrier/iter.
  for (int cix = 0; cix <= 127; ++cix) {
    if (role == 0) {
      const int cs = cix + 1;  // chunk to stage this iteration
      const bool dostage = (cs <= 124);
      float sv[5];
      if (dostage) {  // issue global loads early; LDS writes after compute
#pragma unroll
        for (int i = 0; i < 5; ++i)
          sv[i] = x[cbase + (long long)(cs * 16 + st_t[i]) * Fn + st_d[i]];
      }
      if (cix <= 124) {
        const float* xsp = &xs[(cix * 16) & 127][0];
        float* xwp = &xw0[(cix * 16) & 31][0];
#pragma unroll
        for (int p = 0; p < 16; ++p)
          proj2(&xsp[p * 20], WPA, WPB, bzA, bzB, &xwp[p * 128 + lane],
                &xwp[p * 128 + 64 + lane]);
      }
      if (dostage) {
        float* xsw = &xs[(cs * 16) & 127][0];
#pragma unroll
        for (int i = 0; i < 5; ++i) xsw[st_t[i] * 20 + st_d[i]] = sv[i];
      }
    } else if (role == 1) {
      if (cix >= 1 && cix <= 125) {
        const float* xwp = &xw0[((cix - 1) * 16) & 31][0];
        float* hrw = &h0r[((cix - 1) * 16) & 31][0];
        float gzA[16], gzB[16];
#pragma unroll
        for (int p = 0; p < 16; ++p) {  // hoist ring reads off the serial path
          gzA[p] = xwp[p * 128 + lane];
          gzB[p] = xwp[p * 128 + 64 + lane];
        }
#pragma unroll
        for (int p = 0; p < 16; ++p) {
          rec2(gzA[p], gzB[p], WPA, WPB, h, c);
          if (wl) hrw[p * 20 + lane] = h;
        }
      }
    } else if (role == 2) {
      if (cix >= 2 && cix <= 126) {
        const float* hrp = &h0r[((cix - 2) * 16) & 31][0];
        float* xwp = &xw1[((cix - 2) * 16) & 31][0];
#pragma unroll
        for (int p = 0; p < 16; ++p)
          proj2(&hrp[p * 20], WPA, WPB, bzA, bzB, &xwp[p * 128 + lane],
                &xwp[p * 128 + 64 + lane]);
      }
    } else {
      if (cix >= 3) {
        const int c16 = (cix - 3) * 16;
        const int rl = wl ? lane : 0;
        const float* xwp = &xw1[c16 & 31][0];
        const float* xsp = &xs[c16 & 127][0];
        float gzA[16], gzB[16], xr[16];
#pragma unroll
        for (int p = 0; p < 16; ++p) {
          gzA[p] = xwp[p * 128 + lane];
          gzB[p] = xwp[p * 128 + 64 + lane];
          xr[p] = xsp[p * 20 + rl];  // residual x
        }
#pragma unroll
        for (int p = 0; p < 16; ++p) {
          rec2(gzA[p], gzB[p], WPA, WPB, h, c);
          if (wl) out[cbase + (long long)(c16 + p) * Fn + lane] = h + xr[p];
        }
      }
    }
    __syncthreads();  // single chunk-boundary barrier (outside role divergence)
  }
}

// ---- one-time weight f32->bf16 conversion into workspace ----
__global__ __launch_bounds__(256) void wprep_kernel(
    const float* __restrict__ W1, const float* __restrict__ W2,
    unsigned short* __restrict__ wb) {
  const int t = blockIdx.x * 256 + threadIdx.x;  // 51200 threads x 4 elems
  const float4 v = (t < 25600) ? *(const float4*)(W1 + t * 4)
                               : *(const float4*)(W2 + (t - 25600) * 4);
  *(ushort4*)(wb + t * 4) =
      make_ushort4(f2bf(v.x), f2bf(v.y), f2bf(v.z), f2bf(v.w));
}

// ---- MFMA bf16 MLP, preconverted bf16 weights (R10-proven, ~165us) ----
__global__ __launch_bounds__(256) void mlp_bf16w_kernel(
    float* io, const unsigned short* __restrict__ wb,
    const float* __restrict__ b1, const float* __restrict__ b2) {
  __shared__ short Ab[64 * 168];
  __shared__ short Wb[64 * 168];
  __shared__ short Hb[64 * 72];
  __shared__ short W2b[160 * 72];
  const unsigned short* __restrict__ W1b = wb + WS_W1;
  const unsigned short* __restrict__ W2s = wb + WS_W2;
  const int tid = threadIdx.x;
  const int lane = tid & 63;
  const int wv = tid >> 6;
  const long long r0 = (long long)blockIdx.x * 64;

#pragma unroll
  for (int i = 0; i < 10; ++i) {
    const int idx = tid + i * 256;
    const int r = idx / 40, kq = idx % 40;
    const float4 v = *(const float4*)(io + (r0 + r) * Fn + kq * 4);
    *(ushort4*)&Ab[r * 168 + kq * 4] =
        make_ushort4(f2bf(v.x), f2bf(v.y), f2bf(v.z), f2bf(v.w));
  }
  __syncthreads();

  const int cl = lane & 15;
  const int q8 = (lane >> 4) * 8;
  const int ar = wv * 16 + cl;
  bf16x8 afr[5];
#pragma unroll
  for (int kk = 0; kk < 5; ++kk)
    afr[kk] = *(const bf16x8*)&Ab[ar * 168 + kk * 32 + q8];

  f32x4 acc[10];
#pragma unroll
  for (int n = 0; n < 10; ++n) acc[n] = (f32x4){0.f, 0.f, 0.f, 0.f};

  for (int nc = 0; nc < 10; ++nc) {
    if (nc) __syncthreads();
#pragma unroll
    for (int i = 0; i < 10; ++i) {  // Wb: 64 rows x 160 bf16, plain copy
      const int idx = tid + i * 256;
      const int r = idx / 40, kq = idx % 40;
      *(ushort4*)&Wb[r * 168 + kq * 4] =
          *(const ushort4*)(W1b + (nc * 64 + r) * 160 + kq * 4);
    }
#pragma unroll
    for (int i = 0; i < 10; ++i) {  // W2b: 160 rows x 64 bf16, plain copy
      const int idx = tid + i * 256;
      const int n = idx >> 4, kq = idx & 15;
      *(ushort4*)&W2b[n * 72 + kq * 4] =
          *(const ushort4*)(W2s + n * 640 + nc * 64 + kq * 4);
    }
    __syncthreads();
#pragma unroll
    for (int n16 = 0; n16 < 4; ++n16) {
      f32x4 hcc = (f32x4){0.f, 0.f, 0.f, 0.f};
      const int br = n16 * 16 + cl;
#pragma unroll
      for (int kk = 0; kk < 5; ++kk) {
        const bf16x8 bfr = *(const bf16x8*)&Wb[br * 168 + kk * 32 + q8];
        hcc = __builtin_amdgcn_mfma_f32_16x16x32_bf16(afr[kk], bfr, hcc, 0, 0, 0);
      }
      const float b1v = b1[nc * 64 + n16 * 16 + cl];
      const int hrow0 = wv * 16 + (lane >> 4) * 4;
      const int hcol = n16 * 16 + cl;
#pragma unroll
      for (int r = 0; r < 4; ++r)
        Hb[(hrow0 + r) * 72 + hcol] = f2bf(fmaxf(hcc[r] + b1v, 0.f));
    }
    bf16x8 a2[2];
#pragma unroll
    for (int kk = 0; kk < 2; ++kk)
      a2[kk] = *(const bf16x8*)&Hb[ar * 72 + kk * 32 + q8];
#pragma unroll
    for (int n16 = 0; n16 < 10; ++n16) {
      const int br = n16 * 16 + cl;
#pragma unroll
      for (int kk = 0; kk < 2; ++kk) {
        const bf16x8 b2f = *(const bf16x8*)&W2b[br * 72 + kk * 32 + q8];
        acc[n16] = __builtin_amdgcn_mfma_f32_16x16x32_bf16(a2[kk], b2f, acc[n16], 0, 0, 0);
      }
    }
  }
  const int orow0 = wv * 16 + (lane >> 4) * 4;
#pragma unroll
  for (int n16 = 0; n16 < 10; ++n16) {
    const float b2v = b2[n16 * 16 + cl];
#pragma unroll
    for (int r = 0; r < 4; ++r)
      io[(r0 + orow0 + r) * Fn + n16 * 16 + cl] = acc[n16][r] + b2v;
  }
}

// ---- fallback MLP (R9-proven): f32 weights, per-block conversion ----
__global__ __launch_bounds__(256) void mlp_mfma_kernel(
    float* io, const float* __restrict__ W1, const float* __restrict__ b1,
    const float* __restrict__ W2, const float* __restrict__ b2) {
  __shared__ short Ab[64 * 168];
  __shared__ short Wb[64 * 168];
  __shared__ short Hb[64 * 72];
  __shared__ short W2b[160 * 72];
  const int tid = threadIdx.x;
  const int lane = tid & 63;
  const int wv = tid >> 6;
  const long long r0 = (long long)blockIdx.x * 64;

#pragma unroll
  for (int i = 0; i < 10; ++i) {
    const int idx = tid + i * 256;
    const int r = idx / 40, kq = idx % 40;
    const float4 v = *(const float4*)(io + (r0 + r) * Fn + kq * 4);
    *(ushort4*)&Ab[r * 168 + kq * 4] =
        make_ushort4(f2bf(v.x), f2bf(v.y), f2bf(v.z), f2bf(v.w));
  }
  __syncthreads();

  const int cl = lane & 15;
  const int q8 = (lane >> 4) * 8;
  const int ar = wv * 16 + cl;
  bf16x8 afr[5];
#pragma unroll
  for (int kk = 0; kk < 5; ++kk)
    afr[kk] = *(const bf16x8*)&Ab[ar * 168 + kk * 32 + q8];

  f32x4 acc[10];
#pragma unroll
  for (int n = 0; n < 10; ++n) acc[n] = (f32x4){0.f, 0.f, 0.f, 0.f};

  for (int nc = 0; nc < 10; ++nc) {
    if (nc) __syncthreads();
#pragma unroll
    for (int i = 0; i < 10; ++i) {
      const int idx = tid + i * 256;
      const int r = idx / 40, kq = idx % 40;
      const float4 v = *(const float4*)(W1 + (nc * 64 + r) * Fn + kq * 4);
      *(ushort4*)&Wb[r * 168 + kq * 4] =
          make_ushort4(f2bf(v.x), f2bf(v.y), f2bf(v.z), f2bf(v.w));
    }
#pragma unroll
    for (int i = 0; i < 10; ++i) {
      const int idx = tid + i * 256;
      const int n = idx >> 4, kq = idx & 15;
      const float4 v = *(const float4*)(W2 + n * 640 + nc * 64 + kq * 4);
      *(ushort4*)&W2b[n * 72 + kq * 4] =
          make_ushort4(f2bf(v.x), f2bf(v.y), f2bf(v.z), f2bf(v.w));
    }
    __syncthreads();
#pragma unroll
    for (int n16 = 0; n16 < 4; ++n16) {
      f32x4 hcc = (f32x4){0.f, 0.f, 0.f, 0.f};
      const int br = n16 * 16 + cl;
#pragma unroll
      for (int kk = 0; kk < 5; ++kk) {
        const bf16x8 bfr = *(const bf16x8*)&Wb[br * 168 + kk * 32 + q8];
        hcc = __builtin_amdgcn_mfma_f32_16x16x32_bf16(afr[kk], bfr, hcc, 0, 0, 0);
      }
      const float b1v = b1[nc * 64 + n16 * 16 + cl];
      const int hrow0 = wv * 16 + (lane >> 4) * 4;
      const int hcol = n16 * 16 + cl;
#pragma unroll
      for (int r = 0; r < 4; ++r)
        Hb[(hrow0 + r) * 72 + hcol] = f2bf(fmaxf(hcc[r] + b1v, 0.f));
    }
    bf16x8 a2[2];
#pragma unroll
    for (int kk = 0; kk < 2; ++kk)
      a2[kk] = *(const bf16x8*)&Hb[ar * 72 + kk * 32 + q8];
#pragma unroll
    for (int n16 = 0; n16 < 10; ++n16) {
      const int br = n16 * 16 + cl;
#pragma unroll
      for (int kk = 0; kk < 2; ++kk) {
        const bf16x8 b2f = *(const bf16x8*)&W2b[br * 72 + kk * 32 + q8];
        acc[n16] = __builtin_amdgcn_mfma_f32_16x16x32_bf16(a2[kk], b2f, acc[n16], 0, 0, 0);
      }
    }
  }
  const int orow0 = wv * 16 + (lane >> 4) * 4;
#pragma unroll
  for (int n16 = 0; n16 < 10; ++n16) {
    const float b2v = b2[n16 * 16 + cl];
#pragma unroll
    for (int r = 0; r < 4; ++r)
      io[(r0 + orow0 + r) * Fn + n16 * 16 + cl] = acc[n16][r] + b2v;
  }
}

extern "C" void kernel_launch(void* const* d_in, const int* in_sizes, int n_in,
                              void* d_out, int out_size, void* d_ws, size_t ws_size,
                              hipStream_t stream) {
  const float* x    = (const float*)d_in[0];
  const float* Wih0 = (const float*)d_in[1];
  const float* Whh0 = (const float*)d_in[2];
  const float* bih0 = (const float*)d_in[3];
  const float* bhh0 = (const float*)d_in[4];
  const float* Wih1 = (const float*)d_in[5];
  const float* Whh1 = (const float*)d_in[6];
  const float* bih1 = (const float*)d_in[7];
  const float* bhh1 = (const float*)d_in[8];
  const float* W1   = (const float*)d_in[9];
  const float* b1   = (const float*)d_in[10];
  const float* W2   = (const float*)d_in[11];
  const float* b2   = (const float*)d_in[12];
  float* out = (float*)d_out;

  const bool fast = (d_ws != nullptr) && (ws_size >= WS_NEED);
  if (fast)  // weight conversion first (no dependence on scan output)
    wprep_kernel<<<dim3(200), dim3(256), 0, stream>>>(
        W1, W2, (unsigned short*)d_ws);

  scan4p_kernel<<<dim3(256), dim3(512), 0, stream>>>(
      x, Wih0, Whh0, bih0, bhh0, Wih1, Whh1, bih1, bhh1, out);

  if (fast)
    mlp_bf16w_kernel<<<dim3(NR / 64), dim3(256), 0, stream>>>(
        out, (const unsigned short*)d_ws, b1, b2);
  else
    mlp_mfma_kernel<<<dim3(NR / 64), dim3(256), 0, stream>>>(out, W1, b1, W2, b2);
}